// Round 1
// baseline (56016.333 us; speedup 1.0000x reference)
//
#include <hip/hip_runtime.h>
#include <hip/hip_bf16.h>

#define DEVFN __device__ __forceinline__

// problem constants
static constexpr int Bsz = 8, Tlen = 96, Edim = 256, Hdim = 2048, Pdim = 256;

// ---- workspace layout (bytes) ----
static constexpr size_t OFF_CTRS   = 0;          // 2 layers * 2 dirs * 65 ints = 1040 B (zeroed)
static constexpr size_t OFF_FLAG   = 1280;       // int dtype flag (0=fp32 inputs, 1=bf16 inputs)
static constexpr size_t OFF_STATS  = 1536;       // 8*3*2 floats
static constexpr size_t OFF_EW     = 1792;       // elmo_w[3], gamma -> 4 floats
static constexpr size_t OFF_MASK32 = 2048;       // 768 floats
static constexpr size_t OFF_EMB    = 8192;                         // 768*256 f      = 786,432 B
static constexpr size_t OFF_WR32   = 794624;                       // 4*256*8192 f   = 33,554,432 B
static constexpr size_t OFF_WPT    = 34349056;                     // 4*256*2048 f   = 8,388,608 B
static constexpr size_t OFF_BIAS   = 42737664;                     // 4*8192 f       = 131,072 B
static constexpr size_t OFF_XW     = 42868736;                     // 2*96*8*8192 f  = 50,331,648 B
static constexpr size_t OFF_OUT0   = 93200384;                     // 2*8*96*256 f   = 1,572,864 B
static constexpr size_t OFF_OUT1   = 94773248;                     // 1,572,864 B
static constexpr size_t OFF_Y      = 96346112;                     // 2*8*2048 f     = 131,072 B
static constexpr size_t OFF_H      = 96477184;                     // 2*2*8*256 f    = 32,768 B
// total ~96.5 MB

template<int BF>
DEVFN float ldin(const void* p, size_t i) {
  if (BF) {
    unsigned short u = ((const unsigned short*)p)[i];
    return __uint_as_float(((unsigned)u) << 16);   // bf16 -> fp32 exact
  }
  return ((const float*)p)[i];
}

DEVFN float sigm(float x) { return 1.f / (1.f + __expf(-x)); }
DEVFN float clip3(float x) { return fminf(fmaxf(x, -3.f), 3.f); }

// ---------------- dtype detection ----------------
__global__ void detect_k(const unsigned* mask_raw, int* flagp) {
  if (threadIdx.x == 0) *flagp = (mask_raw[0] == 0x3F800000u) ? 0 : 1;
}

// ---------------- convert small tensors to fp32 ----------------
// Wr (8388608), bias (32768), mask (768), elmo_w (3), gamma (1)
template<int BF>
__global__ void convert_k(const int* flagp, const void* Wr, const void* bias, const void* mask,
                          const void* ew, const void* gm,
                          float* Wr32, float* bias32, float* mask32, float* ew32) {
  if (*flagp != BF) return;
  size_t stride = (size_t)gridDim.x * 256;
  for (size_t i = (size_t)blockIdx.x * 256 + threadIdx.x; i < 8422148ull; i += stride) {
    if (i < 8388608ull)       Wr32[i]   = ldin<BF>(Wr, i);
    else if (i < 8421376ull)  bias32[i - 8388608ull] = ldin<BF>(bias, i - 8388608ull);
    else if (i < 8422144ull)  mask32[i - 8421376ull] = ldin<BF>(mask, i - 8421376ull);
    else if (i < 8422147ull)  ew32[i - 8422144ull]   = ldin<BF>(ew, i - 8422144ull);
    else                      ew32[3] = ldin<BF>(gm, 0);
  }
}

// ---------------- Wp transpose: Wp[dl][k][p] -> WpT[dl][p][k] (fp32) ----------------
template<int BF>
__global__ void transpose_wp_k(const int* flagp, const void* Wp, float* WpT) {
  if (*flagp != BF) return;
  const int kt = blockIdx.x, pt = blockIdx.y, dl = blockIdx.z;
  __shared__ float tile[64][65];
  const int tid = threadIdx.x;
  for (int it = 0; it < 4; ++it) {
    int lin = it * 1024 + tid * 4;
    int kk = lin >> 6, pp = lin & 63;
    size_t src = ((size_t)(dl * 2048 + kt * 64 + kk)) * 256 + pt * 64 + pp;
    float v0, v1, v2, v3;
    if (BF) {
      const unsigned short* sp = (const unsigned short*)Wp + src;
      v0 = __uint_as_float(((unsigned)sp[0]) << 16);
      v1 = __uint_as_float(((unsigned)sp[1]) << 16);
      v2 = __uint_as_float(((unsigned)sp[2]) << 16);
      v3 = __uint_as_float(((unsigned)sp[3]) << 16);
    } else {
      float4 v = *(const float4*)((const float*)Wp + src);
      v0 = v.x; v1 = v.y; v2 = v.z; v3 = v.w;
    }
    tile[pp + 0][kk] = v0; tile[pp + 1][kk] = v1; tile[pp + 2][kk] = v2; tile[pp + 3][kk] = v3;
  }
  __syncthreads();
  for (int it = 0; it < 4; ++it) {
    int lin = it * 1024 + tid * 4;
    int pr = lin >> 6, kc = lin & 63;
    float4 o;
    o.x = tile[pr][kc + 0]; o.y = tile[pr][kc + 1]; o.z = tile[pr][kc + 2]; o.w = tile[pr][kc + 3];
    *(float4*)(WpT + ((size_t)(dl * 256 + pt * 64 + pr)) * 2048 + kt * 64 + kc) = o;
  }
}

// ---------------- embedding gather ----------------
template<int BF>
__global__ void gather_k(const int* flagp, const int* tokens, const void* et, float* emb) {
  if (*flagp != BF) return;
  const int bt = blockIdx.x;            // b*96+t
  const int tok = tokens[bt];
  emb[(size_t)bt * 256 + threadIdx.x] = ldin<BF>(et, (size_t)tok * 256 + threadIdx.x);
}

// ---------------- xW = x @ Wk[dl] + b[dl]  (per dir; fp32 out) ----------------
// M = 768 (m = t*8+b, t in scan time), N = 8192, K = 256
template<int BF>
__global__ __launch_bounds__(256) void xw_gemm_k(
    const int* __restrict__ flagp, const float* __restrict__ x_fwd, const float* __restrict__ x_bwd,
    const void* __restrict__ Wk, const float* __restrict__ bias32, float* __restrict__ xW, int layer) {
  if (*flagp != BF) return;
  const int nt = blockIdx.x, mt = blockIdx.y, dir = blockIdx.z;
  const int dl = dir * 2 + layer;
  const float* xb = dir ? x_bwd : x_fwd;
  const int tid = threadIdx.x;

  __shared__ float As[16][68];   // [k][m]
  __shared__ float Bs[16][68];   // [k][n]

  float acc[4][4] = {};
  const int tx = tid & 15, ty = tid >> 4;

  const int am = tid >> 2;            // 0..63
  const int ak = (tid & 3) * 4;       // 0,4,8,12
  const int m_glob = mt * 64 + am;
  const int t_ = m_glob >> 3, b_ = m_glob & 7;
  const int tau = dir ? (95 - t_) : t_;
  const float* arow = xb + ((size_t)(b_ * 96 + tau)) * 256;

  const int bk = tid >> 4, bn = (tid & 15) * 4;

  for (int kb = 0; kb < 256; kb += 16) {
    float4 av = *(const float4*)(arow + kb + ak);
    As[ak + 0][am] = av.x; As[ak + 1][am] = av.y; As[ak + 2][am] = av.z; As[ak + 3][am] = av.w;

    size_t bidx = ((size_t)dl * 256 + (kb + bk)) * 8192 + (size_t)nt * 64 + bn;
    float b0, b1, b2, b3;
    if (BF) {
      ushort4 uv = *(const ushort4*)((const unsigned short*)Wk + bidx);
      b0 = __uint_as_float(((unsigned)uv.x) << 16);
      b1 = __uint_as_float(((unsigned)uv.y) << 16);
      b2 = __uint_as_float(((unsigned)uv.z) << 16);
      b3 = __uint_as_float(((unsigned)uv.w) << 16);
    } else {
      float4 fv = *(const float4*)((const float*)Wk + bidx);
      b0 = fv.x; b1 = fv.y; b2 = fv.z; b3 = fv.w;
    }
    Bs[bk][bn + 0] = b0; Bs[bk][bn + 1] = b1; Bs[bk][bn + 2] = b2; Bs[bk][bn + 3] = b3;
    __syncthreads();

#pragma unroll
    for (int kk = 0; kk < 16; ++kk) {
      float a0 = As[kk][ty * 4 + 0], a1 = As[kk][ty * 4 + 1], a2 = As[kk][ty * 4 + 2], a3 = As[kk][ty * 4 + 3];
      float c0 = Bs[kk][tx * 4 + 0], c1 = Bs[kk][tx * 4 + 1], c2 = Bs[kk][tx * 4 + 2], c3 = Bs[kk][tx * 4 + 3];
      acc[0][0] = fmaf(a0, c0, acc[0][0]); acc[0][1] = fmaf(a0, c1, acc[0][1]);
      acc[0][2] = fmaf(a0, c2, acc[0][2]); acc[0][3] = fmaf(a0, c3, acc[0][3]);
      acc[1][0] = fmaf(a1, c0, acc[1][0]); acc[1][1] = fmaf(a1, c1, acc[1][1]);
      acc[1][2] = fmaf(a1, c2, acc[1][2]); acc[1][3] = fmaf(a1, c3, acc[1][3]);
      acc[2][0] = fmaf(a2, c0, acc[2][0]); acc[2][1] = fmaf(a2, c1, acc[2][1]);
      acc[2][2] = fmaf(a2, c2, acc[2][2]); acc[2][3] = fmaf(a2, c3, acc[2][3]);
      acc[3][0] = fmaf(a3, c0, acc[3][0]); acc[3][1] = fmaf(a3, c1, acc[3][1]);
      acc[3][2] = fmaf(a3, c2, acc[3][2]); acc[3][3] = fmaf(a3, c3, acc[3][3]);
    }
    __syncthreads();
  }

  const int n0 = nt * 64 + tx * 4;
#pragma unroll
  for (int i = 0; i < 4; ++i) {
    int m = mt * 64 + ty * 4 + i;
    int tt = m >> 3, bb = m & 7;
    float4 o;
    o.x = acc[i][0] + bias32[dl * 8192 + n0 + 0];
    o.y = acc[i][1] + bias32[dl * 8192 + n0 + 1];
    o.z = acc[i][2] + bias32[dl * 8192 + n0 + 2];
    o.w = acc[i][3] + bias32[dl * 8192 + n0 + 3];
    *(float4*)(xW + (size_t)((dir * 96 + tt) * 8 + bb) * 8192 + n0) = o;
  }
}

// ---------------- persistent LSTM scan (cooperative) ----------------
// grid 512 x 256: dir = blk>>8, g = blk&255. wg owns cells n0 = g*8..+8 and p-output p = g.
DEVFN void wg_barrier(int* gctr, int* root, int* gflag, int g, int bcnt) {
  __threadfence();
  __syncthreads();
  if (threadIdx.x == 0) {
    const int grp = g >> 3;
    int old = __hip_atomic_fetch_add(&gctr[grp], 1, __ATOMIC_RELEASE, __HIP_MEMORY_SCOPE_AGENT);
    if (old == 8 * bcnt - 1)
      __hip_atomic_fetch_add(root, 1, __ATOMIC_ACQ_REL, __HIP_MEMORY_SCOPE_AGENT);
    if ((g & 7) == 0) {
      while (__hip_atomic_load(root, __ATOMIC_ACQUIRE, __HIP_MEMORY_SCOPE_AGENT) < 32 * bcnt)
        __builtin_amdgcn_s_sleep(1);
      __hip_atomic_fetch_add(&gflag[grp], 1, __ATOMIC_RELEASE, __HIP_MEMORY_SCOPE_AGENT);
    } else {
      while (__hip_atomic_load(&gflag[grp], __ATOMIC_ACQUIRE, __HIP_MEMORY_SCOPE_AGENT) < bcnt)
        __builtin_amdgcn_s_sleep(1);
    }
  }
  __syncthreads();
  __threadfence();
}

__global__ __launch_bounds__(256, 2) void scan_kernel(
    const float* __restrict__ xW, const float* __restrict__ Wr32, const float* __restrict__ WpT,
    const float* __restrict__ mask32, float* __restrict__ out, float* __restrict__ hbuf,
    float* __restrict__ y, int* ctrs, int layer) {
  const int tid = threadIdx.x;
  const int w = blockIdx.x;
  const int dir = w >> 8;
  const int g = w & 255;
  const int dl = dir * 2 + layer;

  __shared__ float  h_lds[2048];
  __shared__ float4 zred[256];
  __shared__ float  z_s[8][4][8];   // [b][gate][cell]
  __shared__ float  c_s[64];        // [b*8+cell]
  __shared__ float  wp_s[2048];
  __shared__ float  red[256];

  int* base  = ctrs + (layer * 2 + dir) * 65;
  int* gctr  = base;
  int* root  = base + 32;
  int* gflag = base + 33;
  int bcnt = 0;

  for (int i = tid; i < 2048; i += 256)
    wp_s[i] = WpT[((size_t)(dl * 256 + g)) * 2048 + i];
  if (tid < 64) c_s[tid] = 0.f;

  const int u = tid >> 2, ks = tid & 3;
  const int ub = u >> 3, ugate = (u >> 1) & 3, uq = u & 1;
  const int colq = ugate * 512 + g * 2 + uq;  // float4 index within 2048
  const float4* wr4 = (const float4*)(Wr32 + (size_t)dl * 256 * 8192);
  float* ydir = y + dir * 16384;

  for (int t = 0; t < 96; ++t) {
    const int tau = dir ? (95 - t) : t;

    if (t == 0) {
      for (int i = tid; i < 2048; i += 256) h_lds[i] = 0.f;
    } else {
      const float* hb = hbuf + ((size_t)((t & 1) * 2 + dir)) * 2048;
      for (int i = tid; i < 2048; i += 256) h_lds[i] = hb[i];
    }
    __syncthreads();

    // ---- phase 1: z = xW[t] + h @ Wr, gates, cell, y ----
    float4 acc = make_float4(0.f, 0.f, 0.f, 0.f);
    const float* hrow = h_lds + ub * 256;
    const int k0 = ks * 64;
#pragma unroll 8
    for (int k = k0; k < k0 + 64; ++k) {
      float hv = hrow[k];
      float4 wv = wr4[(size_t)k * 2048 + colq];
      acc.x = fmaf(hv, wv.x, acc.x); acc.y = fmaf(hv, wv.y, acc.y);
      acc.z = fmaf(hv, wv.z, acc.z); acc.w = fmaf(hv, wv.w, acc.w);
    }
    zred[tid] = acc;
    __syncthreads();

    if (tid < 64) {
      float4 s0 = zred[tid * 4 + 0], s1 = zred[tid * 4 + 1], s2 = zred[tid * 4 + 2], s3 = zred[tid * 4 + 3];
      float sx = s0.x + s1.x + s2.x + s3.x;
      float sy = s0.y + s1.y + s2.y + s3.y;
      float sz = s0.z + s1.z + s2.z + s3.z;
      float sw = s0.w + s1.w + s2.w + s3.w;
      const int b2 = tid >> 3, gate2 = (tid >> 1) & 3, q2 = tid & 1;
      const int colq2 = gate2 * 512 + g * 2 + q2;
      float4 xv = ((const float4*)xW)[(size_t)((dir * 96 + t) * 8 + b2) * 2048 + colq2];
      z_s[b2][gate2][q2 * 4 + 0] = sx + xv.x;
      z_s[b2][gate2][q2 * 4 + 1] = sy + xv.y;
      z_s[b2][gate2][q2 * 4 + 2] = sz + xv.z;
      z_s[b2][gate2][q2 * 4 + 3] = sw + xv.w;
    }
    __syncthreads();

    if (tid < 64) {
      const int b3 = tid >> 3, cell = tid & 7;
      float zi = z_s[b3][0][cell], zf = z_s[b3][1][cell], zg = z_s[b3][2][cell], zo = z_s[b3][3][cell];
      float ig = sigm(zi), fg = sigm(zf), gg = tanhf(zg), og = sigm(zo);
      float cold = c_s[tid];
      float cc = clip3(fg * cold + ig * gg);
      float yv = og * tanhf(cc);
      float m = mask32[b3 * 96 + tau];
      c_s[tid] = (m > 0.f) ? cc : cold;
      ydir[b3 * 2048 + g * 8 + cell] = yv;
    }
    wg_barrier(gctr, root, gflag, g, ++bcnt);

    // ---- phase 2: h = clip(y @ Wp) for p = g, all b ----
    {
      const int b = tid >> 5, kk = tid & 31;
      const float4* yb = (const float4*)(ydir + b * 2048);
      const float4* wp4 = (const float4*)wp_s;
      float f = 0.f;
#pragma unroll 4
      for (int k4 = kk * 16; k4 < kk * 16 + 16; ++k4) {
        float4 yv = yb[k4], wv = wp4[k4];
        f = fmaf(yv.x, wv.x, f); f = fmaf(yv.y, wv.y, f);
        f = fmaf(yv.z, wv.z, f); f = fmaf(yv.w, wv.w, f);
      }
      red[tid] = f;
    }
    __syncthreads();
    if (tid < 8) {
      float s = 0.f;
      for (int i = 0; i < 32; ++i) s += red[tid * 32 + i];
      float hc = clip3(s);
      float m = mask32[tid * 96 + tau];
      float hp = (t == 0) ? 0.f : hbuf[((size_t)((t & 1) * 2 + dir)) * 2048 + tid * 256 + g];
      float hv = (m > 0.f) ? hc : hp;
      hbuf[((size_t)(((t + 1) & 1) * 2 + dir)) * 2048 + tid * 256 + g] = hv;
      out[(size_t)((dir * 8 + tid) * 96 + tau) * 256 + g] = hv;
    }
    wg_barrier(gctr, root, gflag, g, ++bcnt);
  }
}

// ---------------- ELMo mix: stats then weighted sum ----------------
DEVFN float layer_val(int l, int b, int t, int f, const float* emb, const float* out0, const float* out1) {
  const int half = f >> 8, p = f & 255;
  if (l == 0) return emb[(size_t)(b * 96 + t) * 256 + p];
  const size_t o = ((size_t)((half * 8 + b) * 96 + t)) * 256 + p;
  float v = out0[o];
  if (l == 2) v += out1[o];
  return v;
}

__global__ void mixA_k(const float* emb, const float* out0, const float* out1,
                       const float* mask32, float* stats) {
  const int b = blockIdx.x / 3, l = blockIdx.x % 3;
  float s1 = 0.f, s2 = 0.f;
  for (int idx = threadIdx.x; idx < 96 * 512; idx += 256) {
    int t = idx >> 9, f = idx & 511;
    float v = layer_val(l, b, t, f, emb, out0, out1);
    float m = mask32[b * 96 + t];
    s1 += m * v; s2 += m * v * v;
  }
  for (int off = 32; off; off >>= 1) { s1 += __shfl_down(s1, off); s2 += __shfl_down(s2, off); }
  __shared__ float p1[4], p2[4];
  if ((threadIdx.x & 63) == 0) { p1[threadIdx.x >> 6] = s1; p2[threadIdx.x >> 6] = s2; }
  __syncthreads();
  if (threadIdx.x == 0) {
    float S1 = p1[0] + p1[1] + p1[2] + p1[3];
    float S2 = p2[0] + p2[1] + p2[2] + p2[3];
    float num = 0.f;
    for (int t = 0; t < 96; ++t) num += mask32[b * 96 + t];
    float mean = S1 / num;
    float var = S2 / num - 2.f * mean * mean + 512.f * mean * mean;
    stats[(b * 3 + l) * 2 + 0] = mean;
    stats[(b * 3 + l) * 2 + 1] = rsqrtf(var + 1e-12f);
  }
}

__global__ void mixB_k(const int* flagp, const float* emb, const float* out0, const float* out1,
                       const float* stats, const float* ew32, void* outp) {
  const int idx = blockIdx.x * 256 + threadIdx.x;   // < 393216
  const int b = idx / 49152;
  const int r = idx % 49152;
  const int t = r >> 9, f = r & 511;
  float w0 = ew32[0], w1 = ew32[1], w2 = ew32[2], gm = ew32[3];
  float mx = fmaxf(w0, fmaxf(w1, w2));
  float e0 = __expf(w0 - mx), e1 = __expf(w1 - mx), e2 = __expf(w2 - mx);
  float inv = 1.f / (e0 + e1 + e2);
  float wl[3] = {e0 * inv, e1 * inv, e2 * inv};
  float acc = 0.f;
#pragma unroll
  for (int l = 0; l < 3; ++l) {
    float v = layer_val(l, b, t, f, emb, out0, out1);
    acc += wl[l] * (v - stats[(b * 3 + l) * 2]) * stats[(b * 3 + l) * 2 + 1];
  }
  acc *= gm;
  if (*flagp) ((__hip_bfloat16*)outp)[idx] = __float2bfloat16(acc);
  else        ((float*)outp)[idx] = acc;
}

// ---------------- host ----------------
extern "C" void kernel_launch(void* const* d_in, const int* in_sizes, int n_in,
                              void* d_out, int out_size, void* d_ws, size_t ws_size,
                              hipStream_t stream) {
  const int*  tokens = (const int*)d_in[0];
  const void* maskp  = d_in[1];
  const void* embt   = d_in[2];
  const void* Wk     = d_in[3];
  const void* Wr     = d_in[4];
  const void* bias   = d_in[5];
  const void* Wp     = d_in[6];
  const void* ew     = d_in[7];
  const void* gm     = d_in[8];

  char* ws = (char*)d_ws;
  int*   ctrs   = (int*)(ws + OFF_CTRS);
  int*   flagp  = (int*)(ws + OFF_FLAG);
  float* stats  = (float*)(ws + OFF_STATS);
  float* ew32   = (float*)(ws + OFF_EW);
  float* mask32 = (float*)(ws + OFF_MASK32);
  float* emb    = (float*)(ws + OFF_EMB);
  float* wr32   = (float*)(ws + OFF_WR32);
  float* wpt    = (float*)(ws + OFF_WPT);
  float* bias32 = (float*)(ws + OFF_BIAS);
  float* xW     = (float*)(ws + OFF_XW);
  float* out0   = (float*)(ws + OFF_OUT0);
  float* out1   = (float*)(ws + OFF_OUT1);
  float* ybuf   = (float*)(ws + OFF_Y);
  float* hbuf   = (float*)(ws + OFF_H);

  hipMemsetAsync(d_ws, 0, 8192, stream);
  detect_k<<<1, 64, 0, stream>>>((const unsigned*)maskp, flagp);

  convert_k<0><<<4096, 256, 0, stream>>>(flagp, Wr, bias, maskp, ew, gm, wr32, bias32, mask32, ew32);
  convert_k<1><<<4096, 256, 0, stream>>>(flagp, Wr, bias, maskp, ew, gm, wr32, bias32, mask32, ew32);

  transpose_wp_k<0><<<dim3(32, 4, 4), 256, 0, stream>>>(flagp, Wp, wpt);
  transpose_wp_k<1><<<dim3(32, 4, 4), 256, 0, stream>>>(flagp, Wp, wpt);

  gather_k<0><<<768, 256, 0, stream>>>(flagp, tokens, embt, emb);
  gather_k<1><<<768, 256, 0, stream>>>(flagp, tokens, embt, emb);

  // layer 0 projections (input = emb for both dirs)
  xw_gemm_k<0><<<dim3(128, 12, 2), 256, 0, stream>>>(flagp, emb, emb, Wk, bias32, xW, 0);
  xw_gemm_k<1><<<dim3(128, 12, 2), 256, 0, stream>>>(flagp, emb, emb, Wk, bias32, xW, 0);

  int l0 = 0, l1 = 1;
  {
    void* args[] = {&xW, &wr32, &wpt, &mask32, &out0, &hbuf, &ybuf, &ctrs, &l0};
    hipError_t e = hipLaunchCooperativeKernel((void*)scan_kernel, dim3(512), dim3(256), args, 0, stream);
    if (e != hipSuccess)
      scan_kernel<<<512, 256, 0, stream>>>(xW, wr32, wpt, mask32, out0, hbuf, ybuf, ctrs, 0);
  }

  // layer 1 projections (input = out0, per-direction slices)
  float* x_fwd = out0;
  float* x_bwd = out0 + (size_t)8 * 96 * 256;
  xw_gemm_k<0><<<dim3(128, 12, 2), 256, 0, stream>>>(flagp, x_fwd, x_bwd, Wk, bias32, xW, 1);
  xw_gemm_k<1><<<dim3(128, 12, 2), 256, 0, stream>>>(flagp, x_fwd, x_bwd, Wk, bias32, xW, 1);

  {
    void* args[] = {&xW, &wr32, &wpt, &mask32, &out1, &hbuf, &ybuf, &ctrs, &l1};
    hipError_t e = hipLaunchCooperativeKernel((void*)scan_kernel, dim3(512), dim3(256), args, 0, stream);
    if (e != hipSuccess)
      scan_kernel<<<512, 256, 0, stream>>>(xW, wr32, wpt, mask32, out1, hbuf, ybuf, ctrs, 1);
  }

  mixA_k<<<24, 256, 0, stream>>>(emb, out0, out1, mask32, stats);
  mixB_k<<<1536, 256, 0, stream>>>(flagp, emb, out0, out1, stats, ew32, d_out);
}

// Round 2
// 4798.428 us; speedup vs baseline: 11.6739x; 11.6739x over previous
//
#include <hip/hip_runtime.h>
#include <hip/hip_bf16.h>

#define DEVFN __device__ __forceinline__

// ---- workspace layout (bytes) ----
static constexpr size_t OFF_CTRS   = 0;          // 4 sets * 65 ints (zeroed)
static constexpr size_t OFF_FLAG   = 1280;
static constexpr size_t OFF_STATS  = 1536;
static constexpr size_t OFF_EW     = 1792;
static constexpr size_t OFF_MASK32 = 2048;       // 768 floats
static constexpr size_t OFF_EMB    = 8192;                       // 786,432 B
static constexpr size_t OFF_WPT    = 794624;                     // 8,388,608 B
static constexpr size_t OFF_BIAS   = 9183232;                    // 131,072 B
static constexpr size_t OFF_XW     = 9314304;                    // 50,331,648 B
static constexpr size_t OFF_OUT0   = 59645952;                   // 1,572,864 B
static constexpr size_t OFF_OUT1   = 61218816;                   // 1,572,864 B
static constexpr size_t OFF_Y      = 62791680;                   // 96*2*16384*4 = 12,582,912 B
static constexpr size_t OFF_H      = 75374592;                   // 97*2*2048*4  = 1,589,248 B
// total ~77 MB (round 1 used 96.5 MB OK)

template<int BF>
DEVFN float ldin(const void* p, size_t i) {
  if (BF) {
    unsigned short u = ((const unsigned short*)p)[i];
    return __uint_as_float(((unsigned)u) << 16);
  }
  return ((const float*)p)[i];
}
DEVFN float ldraw(const void* p, size_t i, int bf) {
  if (bf) {
    unsigned short u = ((const unsigned short*)p)[i];
    return __uint_as_float(((unsigned)u) << 16);
  }
  return ((const float*)p)[i];
}

DEVFN float sigm(float x) { return 1.f / (1.f + __expf(-x)); }
DEVFN float clip3(float x) { return fminf(fmaxf(x, -3.f), 3.f); }

// ---------------- dtype detection ----------------
__global__ void detect_k(const unsigned* mask_raw, int* flagp) {
  if (threadIdx.x == 0) *flagp = (mask_raw[0] == 0x3F800000u) ? 0 : 1;
}

// ---------------- convert small tensors: bias(32768), mask(768), ew(3), gm(1) ----------------
template<int BF>
__global__ void convert_k(const int* flagp, const void* bias, const void* mask,
                          const void* ew, const void* gm,
                          float* bias32, float* mask32, float* ew32) {
  if (*flagp != BF) return;
  size_t i = (size_t)blockIdx.x * 256 + threadIdx.x;
  if (i >= 33540) return;
  if (i < 32768)       bias32[i] = ldin<BF>(bias, i);
  else if (i < 33536)  mask32[i - 32768] = ldin<BF>(mask, i - 32768);
  else if (i < 33539)  ew32[i - 33536]   = ldin<BF>(ew, i - 33536);
  else                 ew32[3] = ldin<BF>(gm, 0);
}

// ---------------- Wp transpose: Wp[dl][k][p] -> WpT[dl][p][k] ----------------
template<int BF>
__global__ void transpose_wp_k(const int* flagp, const void* Wp, float* WpT) {
  if (*flagp != BF) return;
  const int kt = blockIdx.x, pt = blockIdx.y, dl = blockIdx.z;
  __shared__ float tile[64][65];
  const int tid = threadIdx.x;
  for (int it = 0; it < 4; ++it) {
    int lin = it * 1024 + tid * 4;
    int kk = lin >> 6, pp = lin & 63;
    size_t src = ((size_t)(dl * 2048 + kt * 64 + kk)) * 256 + pt * 64 + pp;
    float v0, v1, v2, v3;
    if (BF) {
      const unsigned short* sp = (const unsigned short*)Wp + src;
      v0 = __uint_as_float(((unsigned)sp[0]) << 16);
      v1 = __uint_as_float(((unsigned)sp[1]) << 16);
      v2 = __uint_as_float(((unsigned)sp[2]) << 16);
      v3 = __uint_as_float(((unsigned)sp[3]) << 16);
    } else {
      float4 v = *(const float4*)((const float*)Wp + src);
      v0 = v.x; v1 = v.y; v2 = v.z; v3 = v.w;
    }
    tile[pp + 0][kk] = v0; tile[pp + 1][kk] = v1; tile[pp + 2][kk] = v2; tile[pp + 3][kk] = v3;
  }
  __syncthreads();
  for (int it = 0; it < 4; ++it) {
    int lin = it * 1024 + tid * 4;
    int pr = lin >> 6, kc = lin & 63;
    float4 o;
    o.x = tile[pr][kc + 0]; o.y = tile[pr][kc + 1]; o.z = tile[pr][kc + 2]; o.w = tile[pr][kc + 3];
    *(float4*)(WpT + ((size_t)(dl * 256 + pt * 64 + pr)) * 2048 + kt * 64 + kc) = o;
  }
}

// ---------------- embedding gather ----------------
template<int BF>
__global__ void gather_k(const int* flagp, const int* tokens, const void* et, float* emb) {
  if (*flagp != BF) return;
  const int bt = blockIdx.x;
  const int tok = tokens[bt];
  emb[(size_t)bt * 256 + threadIdx.x] = ldin<BF>(et, (size_t)tok * 256 + threadIdx.x);
}

// ---------------- xW = x @ Wk[dl] + b[dl] ----------------
template<int BF>
__global__ __launch_bounds__(256) void xw_gemm_k(
    const int* __restrict__ flagp, const float* __restrict__ x_fwd, const float* __restrict__ x_bwd,
    const void* __restrict__ Wk, const float* __restrict__ bias32, float* __restrict__ xW, int layer) {
  if (*flagp != BF) return;
  const int nt = blockIdx.x, mt = blockIdx.y, dir = blockIdx.z;
  const int dl = dir * 2 + layer;
  const float* xb = dir ? x_bwd : x_fwd;
  const int tid = threadIdx.x;

  __shared__ float As[16][68];
  __shared__ float Bs[16][68];

  float acc[4][4] = {};
  const int tx = tid & 15, ty = tid >> 4;

  const int am = tid >> 2;
  const int ak = (tid & 3) * 4;
  const int m_glob = mt * 64 + am;
  const int t_ = m_glob >> 3, b_ = m_glob & 7;
  const int tau = dir ? (95 - t_) : t_;
  const float* arow = xb + ((size_t)(b_ * 96 + tau)) * 256;

  const int bk = tid >> 4, bn = (tid & 15) * 4;

  for (int kb = 0; kb < 256; kb += 16) {
    float4 av = *(const float4*)(arow + kb + ak);
    As[ak + 0][am] = av.x; As[ak + 1][am] = av.y; As[ak + 2][am] = av.z; As[ak + 3][am] = av.w;

    size_t bidx = ((size_t)dl * 256 + (kb + bk)) * 8192 + (size_t)nt * 64 + bn;
    float b0, b1, b2, b3;
    if (BF) {
      ushort4 uv = *(const ushort4*)((const unsigned short*)Wk + bidx);
      b0 = __uint_as_float(((unsigned)uv.x) << 16);
      b1 = __uint_as_float(((unsigned)uv.y) << 16);
      b2 = __uint_as_float(((unsigned)uv.z) << 16);
      b3 = __uint_as_float(((unsigned)uv.w) << 16);
    } else {
      float4 fv = *(const float4*)((const float*)Wk + bidx);
      b0 = fv.x; b1 = fv.y; b2 = fv.z; b3 = fv.w;
    }
    Bs[bk][bn + 0] = b0; Bs[bk][bn + 1] = b1; Bs[bk][bn + 2] = b2; Bs[bk][bn + 3] = b3;
    __syncthreads();

#pragma unroll
    for (int kk = 0; kk < 16; ++kk) {
      float a0 = As[kk][ty * 4 + 0], a1 = As[kk][ty * 4 + 1], a2 = As[kk][ty * 4 + 2], a3 = As[kk][ty * 4 + 3];
      float c0 = Bs[kk][tx * 4 + 0], c1 = Bs[kk][tx * 4 + 1], c2 = Bs[kk][tx * 4 + 2], c3 = Bs[kk][tx * 4 + 3];
      acc[0][0] = fmaf(a0, c0, acc[0][0]); acc[0][1] = fmaf(a0, c1, acc[0][1]);
      acc[0][2] = fmaf(a0, c2, acc[0][2]); acc[0][3] = fmaf(a0, c3, acc[0][3]);
      acc[1][0] = fmaf(a1, c0, acc[1][0]); acc[1][1] = fmaf(a1, c1, acc[1][1]);
      acc[1][2] = fmaf(a1, c2, acc[1][2]); acc[1][3] = fmaf(a1, c3, acc[1][3]);
      acc[2][0] = fmaf(a2, c0, acc[2][0]); acc[2][1] = fmaf(a2, c1, acc[2][1]);
      acc[2][2] = fmaf(a2, c2, acc[2][2]); acc[2][3] = fmaf(a2, c3, acc[2][3]);
      acc[3][0] = fmaf(a3, c0, acc[3][0]); acc[3][1] = fmaf(a3, c1, acc[3][1]);
      acc[3][2] = fmaf(a3, c2, acc[3][2]); acc[3][3] = fmaf(a3, c3, acc[3][3]);
    }
    __syncthreads();
  }

  const int n0 = nt * 64 + tx * 4;
#pragma unroll
  for (int i = 0; i < 4; ++i) {
    int m = mt * 64 + ty * 4 + i;
    int tt = m >> 3, bb = m & 7;
    float4 o;
    o.x = acc[i][0] + bias32[dl * 8192 + n0 + 0];
    o.y = acc[i][1] + bias32[dl * 8192 + n0 + 1];
    o.z = acc[i][2] + bias32[dl * 8192 + n0 + 2];
    o.w = acc[i][3] + bias32[dl * 8192 + n0 + 3];
    *(float4*)(xW + (size_t)((dir * 96 + tt) * 8 + bb) * 8192 + n0) = o;
  }
}

// ---------------- relaxed two-level device barrier (NO cache-invalidating fences) ----------------
// __syncthreads() drains each wave's vmcnt(0) (incl. sc1 write-through stores) before arrival.
DEVFN void wg_barrier(int* gctr, int* root, int* gflag, int g, int bcnt) {
  __syncthreads();
  if (threadIdx.x == 0) {
    const int grp = g >> 3;
    int old = __hip_atomic_fetch_add(&gctr[grp], 1, __ATOMIC_RELAXED, __HIP_MEMORY_SCOPE_AGENT);
    if (old == 8 * bcnt - 1)
      __hip_atomic_fetch_add(root, 1, __ATOMIC_RELAXED, __HIP_MEMORY_SCOPE_AGENT);
    if ((g & 7) == 0) {
      while (__hip_atomic_load(root, __ATOMIC_RELAXED, __HIP_MEMORY_SCOPE_AGENT) < 32 * bcnt)
        __builtin_amdgcn_s_sleep(1);
      __hip_atomic_fetch_add(&gflag[grp], 1, __ATOMIC_RELAXED, __HIP_MEMORY_SCOPE_AGENT);
    } else {
      while (__hip_atomic_load(&gflag[grp], __ATOMIC_RELAXED, __HIP_MEMORY_SCOPE_AGENT) < bcnt)
        __builtin_amdgcn_s_sleep(1);
    }
  }
  __syncthreads();
}

// ---------------- persistent LSTM scan ----------------
// 512 wgs x 256 thr: dir = blk>>8, g = blk&255. Wr slice lives in LDS; cross-wg
// y/h go through per-step-unique global buffers (sc1 stores, plain cached reads).
__global__ __launch_bounds__(256, 2) void scan_kernel(
    const float* __restrict__ xW, const void* __restrict__ WrRaw, const int* __restrict__ flagp,
    const float* __restrict__ WpT, const float* __restrict__ mask32,
    float* __restrict__ out, float* __restrict__ hbuf, float* __restrict__ ybuf,
    int* ctrs, int layer) {
  const int tid = threadIdx.x;
  const int w = blockIdx.x;
  const int dir = w >> 8;
  const int g = w & 255;
  const int dl = dir * 2 + layer;

  __shared__ float  wr_s[256 * 36];   // 36 KB, row-padded (36 floats/row, 32 used)
  __shared__ float  h_lds[2048];
  __shared__ float4 zred[256];
  __shared__ float  z_s[8][4][8];
  __shared__ float  c_s[64];
  __shared__ float  wp_s[2048];
  __shared__ float  red[256];

  int* base  = ctrs + (layer * 2 + dir) * 65;
  int* gctr  = base;
  int* root  = base + 32;
  int* gflag = base + 33;
  int bcnt = 0;

  // one-time preloads
  const int bf = *flagp;
  {
    const size_t wrbase = (size_t)dl * 256 * 8192;
    for (int i = tid; i < 8192; i += 256) {
      int k = i >> 5, c = i & 31;
      size_t gidx = wrbase + (size_t)k * 8192 + (size_t)(c >> 3) * 2048 + g * 8 + (c & 7);
      wr_s[k * 36 + c] = ldraw(WrRaw, gidx, bf);
    }
  }
  for (int i = tid; i < 2048; i += 256)
    wp_s[i] = WpT[((size_t)(dl * 256 + g)) * 2048 + i];
  if (tid < 64) c_s[tid] = 0.f;

  const int u = tid >> 2, ks = tid & 3;
  const int ub = u >> 3, ugate = (u >> 1) & 3, uq = u & 1;
  const int c0 = ugate * 8 + uq * 4;

  for (int t = 0; t < 96; ++t) {
    const int tau = dir ? (95 - t) : t;
    const float* h_cur = hbuf + ((size_t)(t * 2 + dir)) * 2048;
    float* h_nxt = hbuf + ((size_t)((t + 1) * 2 + dir)) * 2048;
    float* y_t   = ybuf + ((size_t)(t * 2 + dir)) * 16384;

    for (int i = tid; i < 2048; i += 256) h_lds[i] = (t == 0) ? 0.f : h_cur[i];
    __syncthreads();

    // ---- phase 1: z = xW[t] + h @ Wr (from LDS), gates, cell, y ----
    {
      float4 acc = make_float4(0.f, 0.f, 0.f, 0.f);
      const float* hrow = h_lds + ub * 256;
#pragma unroll 8
      for (int i = 0; i < 64; ++i) {
        int k = (i << 2) + ks;                     // stride-4 k interleave
        float hv = hrow[k];
        float4 wv = *(const float4*)&wr_s[k * 36 + c0];
        acc.x = fmaf(hv, wv.x, acc.x); acc.y = fmaf(hv, wv.y, acc.y);
        acc.z = fmaf(hv, wv.z, acc.z); acc.w = fmaf(hv, wv.w, acc.w);
      }
      zred[tid] = acc;
    }
    __syncthreads();

    if (tid < 64) {
      float4 s0 = zred[tid * 4 + 0], s1 = zred[tid * 4 + 1], s2 = zred[tid * 4 + 2], s3 = zred[tid * 4 + 3];
      float sx = s0.x + s1.x + s2.x + s3.x;
      float sy = s0.y + s1.y + s2.y + s3.y;
      float sz = s0.z + s1.z + s2.z + s3.z;
      float sw = s0.w + s1.w + s2.w + s3.w;
      const int b2 = tid >> 3, gate2 = (tid >> 1) & 3, q2 = tid & 1;
      const int colq2 = gate2 * 512 + g * 2 + q2;
      float4 xv = ((const float4*)xW)[(size_t)((dir * 96 + t) * 8 + b2) * 2048 + colq2];
      z_s[b2][gate2][q2 * 4 + 0] = sx + xv.x;
      z_s[b2][gate2][q2 * 4 + 1] = sy + xv.y;
      z_s[b2][gate2][q2 * 4 + 2] = sz + xv.z;
      z_s[b2][gate2][q2 * 4 + 3] = sw + xv.w;
    }
    __syncthreads();

    if (tid < 64) {
      const int b3 = tid >> 3, cell = tid & 7;
      float zi = z_s[b3][0][cell], zf = z_s[b3][1][cell], zg = z_s[b3][2][cell], zo = z_s[b3][3][cell];
      float ig = sigm(zi), fg = sigm(zf), gg = tanhf(zg), og = sigm(zo);
      float cold = c_s[tid];
      float cc = clip3(fg * cold + ig * gg);
      float yv = og * tanhf(cc);
      float m = mask32[b3 * 96 + tau];
      c_s[tid] = (m > 0.f) ? cc : cold;
      __hip_atomic_store(&y_t[b3 * 2048 + g * 8 + cell], yv, __ATOMIC_RELAXED, __HIP_MEMORY_SCOPE_AGENT);
    }
    wg_barrier(gctr, root, gflag, g, ++bcnt);

    // ---- phase 2: h[p=g] = clip(y @ Wp) ----  (plain cached reads: y_t is a fresh address)
    {
      const int b = tid >> 5, kk = tid & 31;
      const float4* yb = (const float4*)(y_t + b * 2048);
      const float4* wp4 = (const float4*)wp_s;
      float f = 0.f;
#pragma unroll 4
      for (int k4 = kk * 16; k4 < kk * 16 + 16; ++k4) {
        float4 yv = yb[k4], wv = wp4[k4];
        f = fmaf(yv.x, wv.x, f); f = fmaf(yv.y, wv.y, f);
        f = fmaf(yv.z, wv.z, f); f = fmaf(yv.w, wv.w, f);
      }
      red[tid] = f;
    }
    __syncthreads();
    if (tid < 8) {
      float s = 0.f;
      for (int i = 0; i < 32; ++i) s += red[tid * 32 + i];
      float hc = clip3(s);
      float m = mask32[tid * 96 + tau];
      float hp = (t == 0) ? 0.f : h_cur[tid * 256 + g];
      float hv = (m > 0.f) ? hc : hp;
      __hip_atomic_store(&h_nxt[tid * 256 + g], hv, __ATOMIC_RELAXED, __HIP_MEMORY_SCOPE_AGENT);
      out[(size_t)((dir * 8 + tid) * 96 + tau) * 256 + g] = hv;
    }
    wg_barrier(gctr, root, gflag, g, ++bcnt);
  }
}

// ---------------- ELMo mix ----------------
DEVFN float layer_val(int l, int b, int t, int f, const float* emb, const float* out0, const float* out1) {
  const int half = f >> 8, p = f & 255;
  if (l == 0) return emb[(size_t)(b * 96 + t) * 256 + p];
  const size_t o = ((size_t)((half * 8 + b) * 96 + t)) * 256 + p;
  float v = out0[o];
  if (l == 2) v += out1[o];
  return v;
}

__global__ void mixA_k(const float* emb, const float* out0, const float* out1,
                       const float* mask32, float* stats) {
  const int b = blockIdx.x / 3, l = blockIdx.x % 3;
  float s1 = 0.f, s2 = 0.f;
  for (int idx = threadIdx.x; idx < 96 * 512; idx += 256) {
    int t = idx >> 9, f = idx & 511;
    float v = layer_val(l, b, t, f, emb, out0, out1);
    float m = mask32[b * 96 + t];
    s1 += m * v; s2 += m * v * v;
  }
  for (int off = 32; off; off >>= 1) { s1 += __shfl_down(s1, off); s2 += __shfl_down(s2, off); }
  __shared__ float p1[4], p2[4];
  if ((threadIdx.x & 63) == 0) { p1[threadIdx.x >> 6] = s1; p2[threadIdx.x >> 6] = s2; }
  __syncthreads();
  if (threadIdx.x == 0) {
    float S1 = p1[0] + p1[1] + p1[2] + p1[3];
    float S2 = p2[0] + p2[1] + p2[2] + p2[3];
    float num = 0.f;
    for (int t = 0; t < 96; ++t) num += mask32[b * 96 + t];
    float mean = S1 / num;
    float var = S2 / num - 2.f * mean * mean + 512.f * mean * mean;
    stats[(b * 3 + l) * 2 + 0] = mean;
    stats[(b * 3 + l) * 2 + 1] = rsqrtf(var + 1e-12f);
  }
}

__global__ void mixB_k(const int* flagp, const float* emb, const float* out0, const float* out1,
                       const float* stats, const float* ew32, void* outp) {
  const int idx = blockIdx.x * 256 + threadIdx.x;
  const int b = idx / 49152;
  const int r = idx % 49152;
  const int t = r >> 9, f = r & 511;
  float w0 = ew32[0], w1 = ew32[1], w2 = ew32[2], gm = ew32[3];
  float mx = fmaxf(w0, fmaxf(w1, w2));
  float e0 = __expf(w0 - mx), e1 = __expf(w1 - mx), e2 = __expf(w2 - mx);
  float inv = 1.f / (e0 + e1 + e2);
  float wl[3] = {e0 * inv, e1 * inv, e2 * inv};
  float acc = 0.f;
#pragma unroll
  for (int l = 0; l < 3; ++l) {
    float v = layer_val(l, b, t, f, emb, out0, out1);
    acc += wl[l] * (v - stats[(b * 3 + l) * 2]) * stats[(b * 3 + l) * 2 + 1];
  }
  acc *= gm;
  if (*flagp) ((__hip_bfloat16*)outp)[idx] = __float2bfloat16(acc);
  else        ((float*)outp)[idx] = acc;
}

// ---------------- host ----------------
extern "C" void kernel_launch(void* const* d_in, const int* in_sizes, int n_in,
                              void* d_out, int out_size, void* d_ws, size_t ws_size,
                              hipStream_t stream) {
  const int*  tokens = (const int*)d_in[0];
  const void* maskp  = d_in[1];
  const void* embt   = d_in[2];
  const void* Wk     = d_in[3];
  const void* WrRaw  = d_in[4];
  const void* bias   = d_in[5];
  const void* Wp     = d_in[6];
  const void* ew     = d_in[7];
  const void* gm     = d_in[8];

  char* ws = (char*)d_ws;
  int*   ctrs   = (int*)(ws + OFF_CTRS);
  int*   flagp  = (int*)(ws + OFF_FLAG);
  float* stats  = (float*)(ws + OFF_STATS);
  float* ew32   = (float*)(ws + OFF_EW);
  float* mask32 = (float*)(ws + OFF_MASK32);
  float* emb    = (float*)(ws + OFF_EMB);
  float* wpt    = (float*)(ws + OFF_WPT);
  float* bias32 = (float*)(ws + OFF_BIAS);
  float* xW     = (float*)(ws + OFF_XW);
  float* out0   = (float*)(ws + OFF_OUT0);
  float* out1   = (float*)(ws + OFF_OUT1);
  float* ybuf   = (float*)(ws + OFF_Y);
  float* hbuf   = (float*)(ws + OFF_H);

  hipMemsetAsync(d_ws, 0, 8192, stream);
  detect_k<<<1, 64, 0, stream>>>((const unsigned*)maskp, flagp);

  convert_k<0><<<132, 256, 0, stream>>>(flagp, bias, maskp, ew, gm, bias32, mask32, ew32);
  convert_k<1><<<132, 256, 0, stream>>>(flagp, bias, maskp, ew, gm, bias32, mask32, ew32);

  transpose_wp_k<0><<<dim3(32, 4, 4), 256, 0, stream>>>(flagp, Wp, wpt);
  transpose_wp_k<1><<<dim3(32, 4, 4), 256, 0, stream>>>(flagp, Wp, wpt);

  gather_k<0><<<768, 256, 0, stream>>>(flagp, tokens, embt, emb);
  gather_k<1><<<768, 256, 0, stream>>>(flagp, tokens, embt, emb);

  xw_gemm_k<0><<<dim3(128, 12, 2), 256, 0, stream>>>(flagp, emb, emb, Wk, bias32, xW, 0);
  xw_gemm_k<1><<<dim3(128, 12, 2), 256, 0, stream>>>(flagp, emb, emb, Wk, bias32, xW, 0);

  int l0 = 0, l1 = 1;
  {
    void* args[] = {&xW, &WrRaw, &flagp, &wpt, &mask32, &out0, &hbuf, &ybuf, &ctrs, &l0};
    hipError_t e = hipLaunchCooperativeKernel((void*)scan_kernel, dim3(512), dim3(256), args, 0, stream);
    if (e != hipSuccess)
      scan_kernel<<<512, 256, 0, stream>>>(xW, WrRaw, flagp, wpt, mask32, out0, hbuf, ybuf, ctrs, 0);
  }

  float* x_fwd = out0;
  float* x_bwd = out0 + (size_t)8 * 96 * 256;
  xw_gemm_k<0><<<dim3(128, 12, 2), 256, 0, stream>>>(flagp, x_fwd, x_bwd, Wk, bias32, xW, 1);
  xw_gemm_k<1><<<dim3(128, 12, 2), 256, 0, stream>>>(flagp, x_fwd, x_bwd, Wk, bias32, xW, 1);

  {
    void* args[] = {&xW, &WrRaw, &flagp, &wpt, &mask32, &out1, &hbuf, &ybuf, &ctrs, &l1};
    hipError_t e = hipLaunchCooperativeKernel((void*)scan_kernel, dim3(512), dim3(256), args, 0, stream);
    if (e != hipSuccess)
      scan_kernel<<<512, 256, 0, stream>>>(xW, WrRaw, flagp, wpt, mask32, out1, hbuf, ybuf, ctrs, 1);
  }

  mixA_k<<<24, 256, 0, stream>>>(emb, out0, out1, mask32, stats);
  mixB_k<<<1536, 256, 0, stream>>>(flagp, emb, out0, out1, stats, ew32, d_out);
}

// Round 5
// 2794.914 us; speedup vs baseline: 20.0422x; 1.7168x over previous
//
#include <hip/hip_runtime.h>
#include <hip/hip_bf16.h>

#define DEVFN __device__ __forceinline__

// ---- workspace layout (bytes) ----
// barrier arenas: 4 * 65 counters * 64 ints (each counter on its own 256B slot)
static constexpr size_t OFF_CTRS   = 0;                          // 66,560 B used; 131,072 reserved (zeroed)
static constexpr size_t OFF_FLAG   = 131072;                     // 4 B
static constexpr size_t OFF_STATS  = 131328;                     // 48 floats = 192 B  (ROUND-3 BUG: was given 128 B, clobbered EW)
static constexpr size_t OFF_EW     = 131584;                     // 4 floats
static constexpr size_t OFF_MASK32 = 131840;                     // 768 floats = 3072 B, ends 134912
static constexpr size_t OFF_EMB    = 135168;                     // 786,432 B
static constexpr size_t OFF_WPT    = 921600;                     // 8,388,608 B
static constexpr size_t OFF_BIAS   = 9310208;                    // 131,072 B
static constexpr size_t OFF_XW     = 9441280;                    // 50,331,648 B
static constexpr size_t OFF_OUT0   = 59772928;                   // 1,572,864 B
static constexpr size_t OFF_OUT1   = 61345792;                   // 1,572,864 B
static constexpr size_t OFF_Y      = 62918656;                   // 96*2*16384*4 = 12,582,912 B
static constexpr size_t OFF_H      = 75501568;                   // 97*2*2048*4  = 1,589,248 B
// total ~77 MB

template<int BF>
DEVFN float ldin(const void* p, size_t i) {
  if (BF) {
    unsigned short u = ((const unsigned short*)p)[i];
    return __uint_as_float(((unsigned)u) << 16);
  }
  return ((const float*)p)[i];
}
DEVFN float ldraw(const void* p, size_t i, int bf) {
  if (bf) {
    unsigned short u = ((const unsigned short*)p)[i];
    return __uint_as_float(((unsigned)u) << 16);
  }
  return ((const float*)p)[i];
}

DEVFN float sigm(float x) { return 1.f / (1.f + __expf(-x)); }
DEVFN float clip3(float x) { return fminf(fmaxf(x, -3.f), 3.f); }

// ---------------- dtype detection ----------------
__global__ void detect_k(const unsigned* mask_raw, int* flagp) {
  if (threadIdx.x == 0) *flagp = (mask_raw[0] == 0x3F800000u) ? 0 : 1;
}

// ---------------- convert small tensors ----------------
template<int BF>
__global__ void convert_k(const int* flagp, const void* bias, const void* mask,
                          const void* ew, const void* gm,
                          float* bias32, float* mask32, float* ew32) {
  if (*flagp != BF) return;
  size_t i = (size_t)blockIdx.x * 256 + threadIdx.x;
  if (i >= 33540) return;
  if (i < 32768)       bias32[i] = ldin<BF>(bias, i);
  else if (i < 33536)  mask32[i - 32768] = ldin<BF>(mask, i - 32768);
  else if (i < 33539)  ew32[i - 33536]   = ldin<BF>(ew, i - 33536);
  else                 ew32[3] = ldin<BF>(gm, 0);
}

// ---------------- Wp transpose: Wp[dl][k][p] -> WpT[dl][p][k] ----------------
template<int BF>
__global__ void transpose_wp_k(const int* flagp, const void* Wp, float* WpT) {
  if (*flagp != BF) return;
  const int kt = blockIdx.x, pt = blockIdx.y, dl = blockIdx.z;
  __shared__ float tile[64][65];
  const int tid = threadIdx.x;
  for (int it = 0; it < 4; ++it) {
    int lin = it * 1024 + tid * 4;
    int kk = lin >> 6, pp = lin & 63;
    size_t src = ((size_t)(dl * 2048 + kt * 64 + kk)) * 256 + pt * 64 + pp;
    float v0, v1, v2, v3;
    if (BF) {
      const unsigned short* sp = (const unsigned short*)Wp + src;
      v0 = __uint_as_float(((unsigned)sp[0]) << 16);
      v1 = __uint_as_float(((unsigned)sp[1]) << 16);
      v2 = __uint_as_float(((unsigned)sp[2]) << 16);
      v3 = __uint_as_float(((unsigned)sp[3]) << 16);
    } else {
      float4 v = *(const float4*)((const float*)Wp + src);
      v0 = v.x; v1 = v.y; v2 = v.z; v3 = v.w;
    }
    tile[pp + 0][kk] = v0; tile[pp + 1][kk] = v1; tile[pp + 2][kk] = v2; tile[pp + 3][kk] = v3;
  }
  __syncthreads();
  for (int it = 0; it < 4; ++it) {
    int lin = it * 1024 + tid * 4;
    int pr = lin >> 6, kc = lin & 63;
    float4 o;
    o.x = tile[pr][kc + 0]; o.y = tile[pr][kc + 1]; o.z = tile[pr][kc + 2]; o.w = tile[pr][kc + 3];
    *(float4*)(WpT + ((size_t)(dl * 256 + pt * 64 + pr)) * 2048 + kt * 64 + kc) = o;
  }
}

// ---------------- embedding gather ----------------
template<int BF>
__global__ void gather_k(const int* flagp, const int* tokens, const void* et, float* emb) {
  if (*flagp != BF) return;
  const int bt = blockIdx.x;
  const int tok = tokens[bt];
  emb[(size_t)bt * 256 + threadIdx.x] = ldin<BF>(et, (size_t)tok * 256 + threadIdx.x);
}

// ---------------- xW = x @ Wk[dl] + b[dl] ----------------
template<int BF>
__global__ __launch_bounds__(256) void xw_gemm_k(
    const int* __restrict__ flagp, const float* __restrict__ x_fwd, const float* __restrict__ x_bwd,
    const void* __restrict__ Wk, const float* __restrict__ bias32, float* __restrict__ xW, int layer) {
  if (*flagp != BF) return;
  const int nt = blockIdx.x, mt = blockIdx.y, dir = blockIdx.z;
  const int dl = dir * 2 + layer;
  const float* xb = dir ? x_bwd : x_fwd;
  const int tid = threadIdx.x;

  __shared__ float As[16][68];
  __shared__ float Bs[16][68];

  float acc[4][4] = {};
  const int tx = tid & 15, ty = tid >> 4;

  const int am = tid >> 2;
  const int ak = (tid & 3) * 4;
  const int m_glob = mt * 64 + am;
  const int t_ = m_glob >> 3, b_ = m_glob & 7;
  const int tau = dir ? (95 - t_) : t_;
  const float* arow = xb + ((size_t)(b_ * 96 + tau)) * 256;

  const int bk = tid >> 4, bn = (tid & 15) * 4;

  for (int kb = 0; kb < 256; kb += 16) {
    float4 av = *(const float4*)(arow + kb + ak);
    As[ak + 0][am] = av.x; As[ak + 1][am] = av.y; As[ak + 2][am] = av.z; As[ak + 3][am] = av.w;

    size_t bidx = ((size_t)dl * 256 + (kb + bk)) * 8192 + (size_t)nt * 64 + bn;
    float b0, b1, b2, b3;
    if (BF) {
      ushort4 uv = *(const ushort4*)((const unsigned short*)Wk + bidx);
      b0 = __uint_as_float(((unsigned)uv.x) << 16);
      b1 = __uint_as_float(((unsigned)uv.y) << 16);
      b2 = __uint_as_float(((unsigned)uv.z) << 16);
      b3 = __uint_as_float(((unsigned)uv.w) << 16);
    } else {
      float4 fv = *(const float4*)((const float*)Wk + bidx);
      b0 = fv.x; b1 = fv.y; b2 = fv.z; b3 = fv.w;
    }
    Bs[bk][bn + 0] = b0; Bs[bk][bn + 1] = b1; Bs[bk][bn + 2] = b2; Bs[bk][bn + 3] = b3;
    __syncthreads();

#pragma unroll
    for (int kk = 0; kk < 16; ++kk) {
      float a0 = As[kk][ty * 4 + 0], a1 = As[kk][ty * 4 + 1], a2 = As[kk][ty * 4 + 2], a3 = As[kk][ty * 4 + 3];
      float c0 = Bs[kk][tx * 4 + 0], c1 = Bs[kk][tx * 4 + 1], c2 = Bs[kk][tx * 4 + 2], c3 = Bs[kk][tx * 4 + 3];
      acc[0][0] = fmaf(a0, c0, acc[0][0]); acc[0][1] = fmaf(a0, c1, acc[0][1]);
      acc[0][2] = fmaf(a0, c2, acc[0][2]); acc[0][3] = fmaf(a0, c3, acc[0][3]);
      acc[1][0] = fmaf(a1, c0, acc[1][0]); acc[1][1] = fmaf(a1, c1, acc[1][1]);
      acc[1][2] = fmaf(a1, c2, acc[1][2]); acc[1][3] = fmaf(a1, c3, acc[1][3]);
      acc[2][0] = fmaf(a2, c0, acc[2][0]); acc[2][1] = fmaf(a2, c1, acc[2][1]);
      acc[2][2] = fmaf(a2, c2, acc[2][2]); acc[2][3] = fmaf(a2, c3, acc[2][3]);
      acc[3][0] = fmaf(a3, c0, acc[3][0]); acc[3][1] = fmaf(a3, c1, acc[3][1]);
      acc[3][2] = fmaf(a3, c2, acc[3][2]); acc[3][3] = fmaf(a3, c3, acc[3][3]);
    }
    __syncthreads();
  }

  const int n0 = nt * 64 + tx * 4;
#pragma unroll
  for (int i = 0; i < 4; ++i) {
    int m = mt * 64 + ty * 4 + i;
    int tt = m >> 3, bb = m & 7;
    float4 o;
    o.x = acc[i][0] + bias32[dl * 8192 + n0 + 0];
    o.y = acc[i][1] + bias32[dl * 8192 + n0 + 1];
    o.z = acc[i][2] + bias32[dl * 8192 + n0 + 2];
    o.w = acc[i][3] + bias32[dl * 8192 + n0 + 3];
    *(float4*)(xW + (size_t)((dir * 96 + tt) * 8 + bb) * 8192 + n0) = o;
  }
}

// ---------------- relaxed two-level barrier, padded counters ----------------
// Protocol (validated by round 2's pass; rounds 3/4 failures were a ws-layout
// bug, NOT ordering): cross-wg y/h data is pushed with relaxed AGENT-scope
// atomic stores (bypass writer-XCD L2 straight to the coherence point);
// __syncthreads() before arrival drains vmcnt so those stores have completed;
// barrier counters are relaxed MALL-point atomics; readers use plain cached
// loads of per-step-unique addresses (can never be stale in reader caches).
// NO acquire anywhere (round-1: acquire-in-spin-loop emitted buffer_inv per
// poll = full L2 wipe = 12x regression).
DEVFN void wg_barrier(int* base, int g, int bcnt) {
  __syncthreads();
  if (threadIdx.x == 0) {
    const int grp = g >> 3;
    int* gctr  = base + grp * 64;
    int* root  = base + 32 * 64;
    int* gflag = base + (33 + grp) * 64;
    int old = __hip_atomic_fetch_add(gctr, 1, __ATOMIC_RELAXED, __HIP_MEMORY_SCOPE_AGENT);
    if (old == 8 * bcnt - 1)
      __hip_atomic_fetch_add(root, 1, __ATOMIC_RELAXED, __HIP_MEMORY_SCOPE_AGENT);
    if ((g & 7) == 0) {
      while (__hip_atomic_load(root, __ATOMIC_RELAXED, __HIP_MEMORY_SCOPE_AGENT) < 32 * bcnt)
        __builtin_amdgcn_s_sleep(1);
      __hip_atomic_store(gflag, bcnt, __ATOMIC_RELAXED, __HIP_MEMORY_SCOPE_AGENT);
    } else {
      while (__hip_atomic_load(gflag, __ATOMIC_RELAXED, __HIP_MEMORY_SCOPE_AGENT) < bcnt)
        __builtin_amdgcn_s_sleep(1);
    }
  }
  __syncthreads();
}

// ---------------- persistent LSTM scan ----------------
__global__ __launch_bounds__(256, 2) void scan_kernel(
    const float* __restrict__ xW, const void* __restrict__ WrRaw, const int* __restrict__ flagp,
    const float* __restrict__ WpT, const float* __restrict__ mask32,
    float* __restrict__ out, float* __restrict__ hbuf, float* __restrict__ ybuf,
    int* ctrs, int layer) {
  const int tid = threadIdx.x;
  const int w = blockIdx.x;
  const int dir = w >> 8;
  const int g = w & 255;
  const int dl = dir * 2 + layer;

  __shared__ float  wr_s[256 * 36];
  __shared__ float  h_lds[2048];
  __shared__ float4 zred[256];
  __shared__ float  z_s[8][4][8];
  __shared__ float  c_s[64];
  __shared__ float4 wp_sp[576];     // padded: idx + (idx>>3)
  __shared__ float  red[256];

  int* base = ctrs + (layer * 2 + dir) * 65 * 64;
  int bcnt = 0;

  const int bf = *flagp;
  {
    const size_t wrbase = (size_t)dl * 256 * 8192;
    for (int i = tid; i < 8192; i += 256) {
      int k = i >> 5, c = i & 31;
      size_t gidx = wrbase + (size_t)k * 8192 + (size_t)(c >> 3) * 2048 + g * 8 + (c & 7);
      wr_s[k * 36 + c] = ldraw(WrRaw, gidx, bf);
    }
  }
  {
    const float4* wrow = (const float4*)(WpT + ((size_t)(dl * 256 + g)) * 2048);
    for (int i = tid; i < 512; i += 256)
      wp_sp[i + (i >> 3)] = wrow[i];
  }
  if (tid < 64) c_s[tid] = 0.f;

  const int u = tid >> 2, ks = tid & 3;
  const int ub = u >> 3, ugate = (u >> 1) & 3, uq = u & 1;
  const int c0 = ugate * 8 + uq * 4;

  for (int t = 0; t < 96; ++t) {
    const int tau = dir ? (95 - t) : t;
    const float* h_cur = hbuf + ((size_t)(t * 2 + dir)) * 2048;
    float* h_nxt = hbuf + ((size_t)((t + 1) * 2 + dir)) * 2048;
    float* y_t   = ybuf + ((size_t)(t * 2 + dir)) * 16384;

    for (int i = tid; i < 2048; i += 256) h_lds[i] = (t == 0) ? 0.f : h_cur[i];
    __syncthreads();

    // ---- phase 1: z = xW[t] + h @ Wr (LDS), gates, cell, y ----
    {
      float4 acc = make_float4(0.f, 0.f, 0.f, 0.f);
      const float* hrow = h_lds + ub * 256;
#pragma unroll 8
      for (int i = 0; i < 64; ++i) {
        int k = (i << 2) + ks;
        float hv = hrow[k];
        float4 wv = *(const float4*)&wr_s[k * 36 + c0];
        acc.x = fmaf(hv, wv.x, acc.x); acc.y = fmaf(hv, wv.y, acc.y);
        acc.z = fmaf(hv, wv.z, acc.z); acc.w = fmaf(hv, wv.w, acc.w);
      }
      zred[tid] = acc;
    }
    __syncthreads();

    if (tid < 64) {
      float4 s0 = zred[tid * 4 + 0], s1 = zred[tid * 4 + 1], s2 = zred[tid * 4 + 2], s3 = zred[tid * 4 + 3];
      float sx = s0.x + s1.x + s2.x + s3.x;
      float sy = s0.y + s1.y + s2.y + s3.y;
      float sz = s0.z + s1.z + s2.z + s3.z;
      float sw = s0.w + s1.w + s2.w + s3.w;
      const int b2 = tid >> 3, gate2 = (tid >> 1) & 3, q2 = tid & 1;
      const int colq2 = gate2 * 512 + g * 2 + q2;
      float4 xv = ((const float4*)xW)[(size_t)((dir * 96 + t) * 8 + b2) * 2048 + colq2];
      z_s[b2][gate2][q2 * 4 + 0] = sx + xv.x;
      z_s[b2][gate2][q2 * 4 + 1] = sy + xv.y;
      z_s[b2][gate2][q2 * 4 + 2] = sz + xv.z;
      z_s[b2][gate2][q2 * 4 + 3] = sw + xv.w;
    }
    __syncthreads();

    if (tid < 64) {
      const int b3 = tid >> 3, cell = tid & 7;
      float zi = z_s[b3][0][cell], zf = z_s[b3][1][cell], zg = z_s[b3][2][cell], zo = z_s[b3][3][cell];
      float ig = sigm(zi), fg = sigm(zf), gg = tanhf(zg), og = sigm(zo);
      float cold = c_s[tid];
      float cc = clip3(fg * cold + ig * gg);
      float yv = og * tanhf(cc);
      float m = mask32[b3 * 96 + tau];
      c_s[tid] = (m > 0.f) ? cc : cold;
      __hip_atomic_store(&y_t[b3 * 2048 + g * 8 + cell], yv, __ATOMIC_RELAXED, __HIP_MEMORY_SCOPE_AGENT);
    }
    wg_barrier(base, g, ++bcnt);

    // ---- phase 2: h[p=g] = clip(y @ Wp) ---- strided k4, padded wp
    {
      const int b = tid >> 5, kk = tid & 31;
      const float4* yb = (const float4*)(y_t + b * 2048);
      float f = 0.f;
#pragma unroll 4
      for (int i = 0; i < 16; ++i) {
        int k4 = kk + (i << 5);
        float4 yv = yb[k4];
        float4 wv = wp_sp[k4 + (k4 >> 3)];
        f = fmaf(yv.x, wv.x, f); f = fmaf(yv.y, wv.y, f);
        f = fmaf(yv.z, wv.z, f); f = fmaf(yv.w, wv.w, f);
      }
      red[kk * 8 + b] = f;
    }
    __syncthreads();
    if (tid < 8) {
      float s = 0.f;
#pragma unroll 8
      for (int i = 0; i < 32; ++i) s += red[i * 8 + tid];
      float hc = clip3(s);
      float m = mask32[tid * 96 + tau];
      float hp = (t == 0) ? 0.f : h_cur[tid * 256 + g];
      float hv = (m > 0.f) ? hc : hp;
      __hip_atomic_store(&h_nxt[tid * 256 + g], hv, __ATOMIC_RELAXED, __HIP_MEMORY_SCOPE_AGENT);
      out[(size_t)((dir * 8 + tid) * 96 + tau) * 256 + g] = hv;
    }
    wg_barrier(base, g, ++bcnt);
  }
}

// ---------------- ELMo mix ----------------
DEVFN float layer_val(int l, int b, int t, int f, const float* emb, const float* out0, const float* out1) {
  const int half = f >> 8, p = f & 255;
  if (l == 0) return emb[(size_t)(b * 96 + t) * 256 + p];
  const size_t o = ((size_t)((half * 8 + b) * 96 + t)) * 256 + p;
  float v = out0[o];
  if (l == 2) v += out1[o];
  return v;
}

__global__ void mixA_k(const float* emb, const float* out0, const float* out1,
                       const float* mask32, float* stats) {
  const int b = blockIdx.x / 3, l = blockIdx.x % 3;
  float s1 = 0.f, s2 = 0.f;
  for (int idx = threadIdx.x; idx < 96 * 512; idx += 256) {
    int t = idx >> 9, f = idx & 511;
    float v = layer_val(l, b, t, f, emb, out0, out1);
    float m = mask32[b * 96 + t];
    s1 += m * v; s2 += m * v * v;
  }
  for (int off = 32; off; off >>= 1) { s1 += __shfl_down(s1, off); s2 += __shfl_down(s2, off); }
  __shared__ float p1[4], p2[4];
  if ((threadIdx.x & 63) == 0) { p1[threadIdx.x >> 6] = s1; p2[threadIdx.x >> 6] = s2; }
  __syncthreads();
  if (threadIdx.x == 0) {
    float S1 = p1[0] + p1[1] + p1[2] + p1[3];
    float S2 = p2[0] + p2[1] + p2[2] + p2[3];
    float num = 0.f;
    for (int t = 0; t < 96; ++t) num += mask32[b * 96 + t];
    float mean = S1 / num;
    float var = S2 / num - 2.f * mean * mean + 512.f * mean * mean;
    stats[(b * 3 + l) * 2 + 0] = mean;
    stats[(b * 3 + l) * 2 + 1] = rsqrtf(var + 1e-12f);
  }
}

__global__ void mixB_k(const int* flagp, const float* emb, const float* out0, const float* out1,
                       const float* stats, const float* ew32, void* outp) {
  const int idx = blockIdx.x * 256 + threadIdx.x;
  const int b = idx / 49152;
  const int r = idx % 49152;
  const int t = r >> 9, f = r & 511;
  float w0 = ew32[0], w1 = ew32[1], w2 = ew32[2], gm = ew32[3];
  float mx = fmaxf(w0, fmaxf(w1, w2));
  float e0 = __expf(w0 - mx), e1 = __expf(w1 - mx), e2 = __expf(w2 - mx);
  float inv = 1.f / (e0 + e1 + e2);
  float wl[3] = {e0 * inv, e1 * inv, e2 * inv};
  float acc = 0.f;
#pragma unroll
  for (int l = 0; l < 3; ++l) {
    float v = layer_val(l, b, t, f, emb, out0, out1);
    acc += wl[l] * (v - stats[(b * 3 + l) * 2]) * stats[(b * 3 + l) * 2 + 1];
  }
  acc *= gm;
  if (*flagp) ((__hip_bfloat16*)outp)[idx] = __float2bfloat16(acc);
  else        ((float*)outp)[idx] = acc;
}

// ---------------- host ----------------
extern "C" void kernel_launch(void* const* d_in, const int* in_sizes, int n_in,
                              void* d_out, int out_size, void* d_ws, size_t ws_size,
                              hipStream_t stream) {
  const int*  tokens = (const int*)d_in[0];
  const void* maskp  = d_in[1];
  const void* embt   = d_in[2];
  const void* Wk     = d_in[3];
  const void* WrRaw  = d_in[4];
  const void* bias   = d_in[5];
  const void* Wp     = d_in[6];
  const void* ew     = d_in[7];
  const void* gm     = d_in[8];

  char* ws = (char*)d_ws;
  int*   ctrs   = (int*)(ws + OFF_CTRS);
  int*   flagp  = (int*)(ws + OFF_FLAG);
  float* stats  = (float*)(ws + OFF_STATS);
  float* ew32   = (float*)(ws + OFF_EW);
  float* mask32 = (float*)(ws + OFF_MASK32);
  float* emb    = (float*)(ws + OFF_EMB);
  float* wpt    = (float*)(ws + OFF_WPT);
  float* bias32 = (float*)(ws + OFF_BIAS);
  float* xW     = (float*)(ws + OFF_XW);
  float* out0   = (float*)(ws + OFF_OUT0);
  float* out1   = (float*)(ws + OFF_OUT1);
  float* ybuf   = (float*)(ws + OFF_Y);
  float* hbuf   = (float*)(ws + OFF_H);

  hipMemsetAsync(d_ws, 0, 131072, stream);
  detect_k<<<1, 64, 0, stream>>>((const unsigned*)maskp, flagp);

  convert_k<0><<<132, 256, 0, stream>>>(flagp, bias, maskp, ew, gm, bias32, mask32, ew32);
  convert_k<1><<<132, 256, 0, stream>>>(flagp, bias, maskp, ew, gm, bias32, mask32, ew32);

  transpose_wp_k<0><<<dim3(32, 4, 4), 256, 0, stream>>>(flagp, Wp, wpt);
  transpose_wp_k<1><<<dim3(32, 4, 4), 256, 0, stream>>>(flagp, Wp, wpt);

  gather_k<0><<<768, 256, 0, stream>>>(flagp, tokens, embt, emb);
  gather_k<1><<<768, 256, 0, stream>>>(flagp, tokens, embt, emb);

  xw_gemm_k<0><<<dim3(128, 12, 2), 256, 0, stream>>>(flagp, emb, emb, Wk, bias32, xW, 0);
  xw_gemm_k<1><<<dim3(128, 12, 2), 256, 0, stream>>>(flagp, emb, emb, Wk, bias32, xW, 0);

  int l0 = 0, l1 = 1;
  {
    void* args[] = {&xW, &WrRaw, &flagp, &wpt, &mask32, &out0, &hbuf, &ybuf, &ctrs, &l0};
    hipError_t e = hipLaunchCooperativeKernel((void*)scan_kernel, dim3(512), dim3(256), args, 0, stream);
    if (e != hipSuccess)
      scan_kernel<<<512, 256, 0, stream>>>(xW, WrRaw, flagp, wpt, mask32, out0, hbuf, ybuf, ctrs, 0);
  }

  float* x_fwd = out0;
  float* x_bwd = out0 + (size_t)8 * 96 * 256;
  xw_gemm_k<0><<<dim3(128, 12, 2), 256, 0, stream>>>(flagp, x_fwd, x_bwd, Wk, bias32, xW, 1);
  xw_gemm_k<1><<<dim3(128, 12, 2), 256, 0, stream>>>(flagp, x_fwd, x_bwd, Wk, bias32, xW, 1);

  {
    void* args[] = {&xW, &WrRaw, &flagp, &wpt, &mask32, &out1, &hbuf, &ybuf, &ctrs, &l1};
    hipError_t e = hipLaunchCooperativeKernel((void*)scan_kernel, dim3(512), dim3(256), args, 0, stream);
    if (e != hipSuccess)
      scan_kernel<<<512, 256, 0, stream>>>(xW, WrRaw, flagp, wpt, mask32, out1, hbuf, ybuf, ctrs, 1);
  }

  mixA_k<<<24, 256, 0, stream>>>(emb, out0, out1, mask32, stats);
  mixB_k<<<1536, 256, 0, stream>>>(flagp, emb, out0, out1, stats, ew32, d_out);
}